// Round 21
// baseline (291.620 us; speedup 1.0000x reference)
//
#include <hip/hip_runtime.h>
#include <hip/hip_bf16.h>
#include <math.h>

#define B_   16
#define C_   384
#define C3_  1152
#define HW_  4096
#define NH_  8
#define D_   48

typedef _Float16 f16x8 __attribute__((ext_vector_type(8)));
typedef _Float16 f16x4 __attribute__((ext_vector_type(4)));
typedef _Float16 f16x2 __attribute__((ext_vector_type(2)));
typedef float    f32x4 __attribute__((ext_vector_type(4)));

#define ASM_VMCNT(n) asm volatile("s_waitcnt vmcnt(" #n ")" ::: "memory")

// ---------------- fused: x transpose->fp16 (z<16) + weight conversion (z==16) ----------------
__global__ __launch_bounds__(256) void prep_inputs(
    const float* __restrict__ x, _Float16* __restrict__ xt,
    const float* __restrict__ wqkv, const float* __restrict__ wproj,
    _Float16* __restrict__ oq, _Float16* __restrict__ op)
{
    const int t = threadIdx.x;
    if (blockIdx.z == 16) {               // weight conversion: 384 blocks x 256 thr
        const int nq = C3_ * C_ / 4;      // float4 units
        const int np = C_ * C_ / 4;
        int idx = (blockIdx.y * 64 + blockIdx.x) * 256 + t;
        for (int i = idx; i < nq + np; i += 384 * 256) {
            const float* src; _Float16* dst; int j;
            if (i < nq) { src = wqkv; dst = oq; j = i; }
            else        { src = wproj; dst = op; j = i - nq; }
            float4 v = *(const float4*)&src[(size_t)j * 4];
            f16x4 h = { (_Float16)v.x, (_Float16)v.y, (_Float16)v.z, (_Float16)v.w };
            *(f16x4*)&dst[(size_t)j * 4] = h;
        }
        return;
    }
    const int b  = blockIdx.z;
    const int k0 = blockIdx.y * 64;
    const int n0 = blockIdx.x * 64;
    __shared__ float sm[64][65];
    const float* xb = x + (size_t)b * C_ * HW_;
    _Float16* xtb = xt + (size_t)b * HW_ * C_;
    #pragma unroll
    for (int i = 0; i < 4; ++i) {
        int row = (t >> 4) + i * 16;
        int col = (t & 15) * 4;
        float4 v = *(const float4*)&xb[(size_t)(k0 + row) * HW_ + n0 + col];
        sm[row][col] = v.x; sm[row][col+1] = v.y; sm[row][col+2] = v.z; sm[row][col+3] = v.w;
    }
    __syncthreads();
    #pragma unroll
    for (int i = 0; i < 2; ++i) {
        int nl = (t >> 3) + i * 32;
        int ks = (t & 7) * 8;
        f16x8 h;
        #pragma unroll
        for (int j = 0; j < 8; ++j) h[j] = (_Float16)sm[ks + j][nl];
        *(f16x8*)&xtb[(size_t)(n0 + nl) * C_ + k0 + ks] = h;
    }
}

// ---------------- MFMA GEMM: 128x256 tile, BK=32, TWO buffers (48 KB -> 3 blocks/CU),
// 2 barriers/K-step (round-9 hazard structure), phased inner loop, split coalesced
// LDS-transpose epilogue (8704 B/wave) ----------------
template<int M, bool F32OUT>
__global__ __launch_bounds__(256, 3) void mfma_gemm(
    const _Float16* __restrict__ Wb,
    const _Float16* __restrict__ XT,
    void* __restrict__ Cv, long long xstride, long long cstride)
{
    constexpr int K = 384;
    constexpr int BK = 32;
    constexpr int NSTEP = K / BK;            // 12
    constexpr int MB = M / 128;              // 9 or 3
    __shared__ _Float16 LDS[24576];          // 48 KB: staging, then epilogue transpose
    _Float16* Ash = LDS;                     // [2][128*32] = 16 KB
    _Float16* Bsh = LDS + 2 * 128 * BK;      // [2][256*32] = 32 KB

    // bijective XCD swizzle; logical order: m fastest, then n, then b
    const int nwg = MB * 16 * B_;
    const int cpx = nwg >> 3;
    const int bid = blockIdx.x;
    const int L   = (bid & 7) * cpx + (bid >> 3);
    const int m0  = (L % MB) * 128;
    const int nb  = L / MB;
    const int n0  = (nb & 15) * 256;
    const int b   = nb >> 4;

    const _Float16* __restrict__ XTb = XT + (size_t)b * xstride;
    const int t = threadIdx.x;
    const int l = t & 63, w = t >> 6;
    const int frow = l & 15, kseg16 = l >> 4;

    auto stage = [&](int d, int kt) {
        const int kk = kt * BK;
        #pragma unroll
        for (int i = 0; i < 2; ++i) {            // A: 128 rows x 32 k = 8 KB
            const int u = i * 256 + t;
            const int row = u >> 2, slot = u & 3;
            const int scol = slot ^ (row & 3) ^ ((row >> 2) & 1);
            const _Float16* ga = Wb + (size_t)(m0 + row) * K + kk + scol * 8;
            __builtin_amdgcn_global_load_lds(
                (const __attribute__((address_space(1))) void*)ga,
                (__attribute__((address_space(3))) void*)((char*)(Ash + d * 128 * BK) + u * 16),
                16, 0, 0);
        }
        #pragma unroll
        for (int i = 0; i < 4; ++i) {            // B: 256 rows x 32 k = 16 KB
            const int u = i * 256 + t;
            const int row = u >> 2, slot = u & 3;
            const int scol = slot ^ (row & 3) ^ ((row >> 2) & 1);
            const _Float16* gb = XTb + (size_t)(n0 + row) * K + kk + scol * 8;
            __builtin_amdgcn_global_load_lds(
                (const __attribute__((address_space(1))) void*)gb,
                (__attribute__((address_space(3))) void*)((char*)(Bsh + d * 256 * BK) + u * 16),
                16, 0, 0);
        }
    };

    f32x4 acc[8][4] = {};

    stage(0, 0); stage(1, 1);                    // 12 loads outstanding
    #pragma unroll
    for (int kt = 0; kt < NSTEP; ++kt) {
        const int cur = kt & 1;
        if (kt + 1 < NSTEP) { ASM_VMCNT(6); } else { ASM_VMCNT(0); }
        __builtin_amdgcn_sched_barrier(0);
        __builtin_amdgcn_s_barrier();            // tile kt visible to all waves
        __builtin_amdgcn_sched_barrier(0);

        const _Float16* Abase = &Ash[cur * 128 * BK];
        const _Float16* Bbase = &Bsh[cur * 256 * BK];

        f16x8 bfr[4];
        #pragma unroll
        for (int ni = 0; ni < 4; ++ni) {
            const int rB = w * 64 + ni * 16 + frow;
            const int cs = kseg16 ^ (rB & 3) ^ ((rB >> 2) & 1);
            bfr[ni] = *(const f16x8*)&Bbase[rB * BK + cs * 8];
        }
        f16x8 afb[2];
        {
            const int rA = frow;
            const int cs = kseg16 ^ (rA & 3) ^ ((rA >> 2) & 1);
            afb[0] = *(const f16x8*)&Abase[rA * BK + cs * 8];
        }
        __builtin_amdgcn_sched_group_barrier(0x100, 5, 0);   // 5 DS_READ (prologue)
        __builtin_amdgcn_s_setprio(1);
        #pragma unroll
        for (int mi = 0; mi < 8; ++mi) {
            if (mi + 1 < 8) {
                const int rA = (mi + 1) * 16 + frow;
                const int cs = kseg16 ^ (rA & 3) ^ ((rA >> 2) & 1);
                afb[(mi + 1) & 1] = *(const f16x8*)&Abase[rA * BK + cs * 8];
            }
            #pragma unroll
            for (int ni = 0; ni < 4; ++ni)
                acc[mi][ni] = __builtin_amdgcn_mfma_f32_16x16x32_f16(
                    bfr[ni], afb[mi & 1], acc[mi][ni], 0, 0, 0);   // D[pixel][channel]
            if (mi + 1 < 8)
                __builtin_amdgcn_sched_group_barrier(0x100, 1, 0); // 1 DS_READ
            __builtin_amdgcn_sched_group_barrier(0x008, 4, 0);     // 4 MFMA
        }
        __builtin_amdgcn_s_setprio(0);
        asm volatile("s_waitcnt lgkmcnt(0)" ::: "memory");
        __builtin_amdgcn_sched_barrier(0);
        __builtin_amdgcn_s_barrier();            // all waves done reading buf[cur]
        if (kt + 2 < NSTEP) stage(cur, kt + 2);
    }

    // ---- split coalesced epilogue: per-wave LDS transpose, 8704 B/wave ----
    __syncthreads();                             // staging LDS dead across all waves
    char* tbase = (char*)LDS + w * 8704;         // 4 x 8704 = 34816 <= 49152
    if constexpr (!F32OUT) {
        _Float16* Co = (_Float16*)Cv + (size_t)b * cstride;
        #pragma unroll
        for (int p = 0; p < 2; ++p) {            // 64 ch x 64 px per pass
            if (p) { asm volatile("s_waitcnt lgkmcnt(0)" ::: "memory");
                     __builtin_amdgcn_sched_barrier(0); }
            #pragma unroll
            for (int mi2 = 0; mi2 < 4; ++mi2)
                #pragma unroll
                for (int ni = 0; ni < 4; ++ni) {
                    const int mi  = p * 4 + mi2;
                    const int row = mi2 * 16 + (l & 15);
                    const int pxl = ni * 16 + (l >> 4) * 4;
                    f16x2 lo = { (_Float16)acc[mi][ni][0], (_Float16)acc[mi][ni][1] };
                    f16x2 hi = { (_Float16)acc[mi][ni][2], (_Float16)acc[mi][ni][3] };
                    *(f16x2*)(tbase + row * 136 + pxl * 2)     = lo;
                    *(f16x2*)(tbase + row * 136 + pxl * 2 + 4) = hi;
                }
            asm volatile("s_waitcnt lgkmcnt(0)" ::: "memory");
            __builtin_amdgcn_sched_barrier(0);
            #pragma unroll
            for (int j = 0; j < 8; ++j) {
                const int lch = j * 8 + (l >> 3);
                const int ch  = p * 64 + lch;
                const int px  = (l & 7) * 8;
                f16x4 lo = *(const f16x4*)(tbase + lch * 136 + px * 2);
                f16x4 hi = *(const f16x4*)(tbase + lch * 136 + px * 2 + 8);
                f16x8 v;
                #pragma unroll
                for (int q = 0; q < 4; ++q) { v[q] = lo[q]; v[q + 4] = hi[q]; }
                *(f16x8*)&Co[(size_t)(m0 + ch) * HW_ + n0 + w * 64 + px] = v;
            }
        }
    } else {
        float* Co = (float*)Cv + (size_t)b * cstride;
        #pragma unroll
        for (int p = 0; p < 4; ++p) {            // 32 ch x 64 px per pass
            if (p) { asm volatile("s_waitcnt lgkmcnt(0)" ::: "memory");
                     __builtin_amdgcn_sched_barrier(0); }
            #pragma unroll
            for (int mi2 = 0; mi2 < 2; ++mi2)
                #pragma unroll
                for (int ni = 0; ni < 4; ++ni) {
                    const int mi  = p * 2 + mi2;
                    const int row = mi2 * 16 + (l & 15);
                    const int pxl = ni * 16 + (l >> 4) * 4;
                    float2 lo = make_float2(acc[mi][ni][0], acc[mi][ni][1]);
                    float2 hi = make_float2(acc[mi][ni][2], acc[mi][ni][3]);
                    *(float2*)(tbase + row * 272 + pxl * 4)     = lo;
                    *(float2*)(tbase + row * 272 + pxl * 4 + 8) = hi;
                }
            asm volatile("s_waitcnt lgkmcnt(0)" ::: "memory");
            __builtin_amdgcn_sched_barrier(0);
            #pragma unroll
            for (int j = 0; j < 8; ++j) {
                const int lch = j * 4 + (l >> 4);
                const int ch  = p * 32 + lch;
                const int px  = (l & 15) * 4;
                float2 lo = *(const float2*)(tbase + lch * 272 + px * 4);
                float2 hi = *(const float2*)(tbase + lch * 272 + px * 4 + 8);
                f32x4 v = { lo.x, lo.y, hi.x, hi.y };
                *(f32x4*)&Co[(size_t)(m0 + ch) * HW_ + n0 + w * 64 + px] = v;
            }
        }
    }
}

// ---------------- depthwise 3x3 SAME in-place (fp16) + fused q/k row-norms ----------------
__global__ __launch_bounds__(256) void dwconv_norm(
    _Float16* __restrict__ buf, const float* __restrict__ wdw,
    float* __restrict__ nqinv, float* __restrict__ nkinv)
{
    const int plane = blockIdx.x;
    const int ch = plane % C3_, b = plane / C3_;
    __shared__ _Float16 smh[64 * 72];
    __shared__ float wsum[4];
    _Float16* g = buf + (size_t)plane * HW_;
    const int t = threadIdx.x;
    #pragma unroll
    for (int i = 0; i < 2; ++i) {
        const int u = i * 256 + t;
        f16x8 v = *(const f16x8*)&g[u * 8];
        *(f16x8*)&smh[(u >> 3) * 72 + (u & 7) * 8] = v;
    }
    float w[9];
    #pragma unroll
    for (int j = 0; j < 9; ++j) w[j] = wdw[ch * 9 + j];
    __syncthreads();
    float ssq = 0.f;
    #pragma unroll
    for (int i = 0; i < 2; ++i) {
        const int u = i * 256 + t;
        const int y = u >> 3, c0 = (u & 7) * 8;
        float r[3][10];
        #pragma unroll
        for (int dy = 0; dy < 3; ++dy) {
            const int yy = y + dy - 1;
            if (yy < 0 || yy > 63) {
                #pragma unroll
                for (int j = 0; j < 10; ++j) r[dy][j] = 0.f;
            } else {
                f16x8 v = *(const f16x8*)&smh[yy * 72 + c0];
                #pragma unroll
                for (int j = 0; j < 8; ++j) r[dy][j + 1] = (float)v[j];
                r[dy][0] = (c0 > 0)  ? (float)smh[yy * 72 + c0 - 1] : 0.f;
                r[dy][9] = (c0 < 56) ? (float)smh[yy * 72 + c0 + 8] : 0.f;
            }
        }
        f16x8 o;
        #pragma unroll
        for (int j = 0; j < 8; ++j) {
            float s = 0.f;
            #pragma unroll
            for (int dy = 0; dy < 3; ++dy)
                #pragma unroll
                for (int dx = 0; dx < 3; ++dx)
                    s = fmaf(w[dy * 3 + dx], r[dy][j + dx], s);
            o[j] = (_Float16)s;
            ssq = fmaf(s, s, ssq);
        }
        *(f16x8*)&g[u * 8] = o;
    }
    if (ch < 2 * C_) {
        #pragma unroll
        for (int m = 1; m < 64; m <<= 1) ssq += __shfl_xor(ssq, m);
        if ((t & 63) == 0) wsum[t >> 6] = ssq;
        __syncthreads();
        if (t == 0) {
            float tot = wsum[0] + wsum[1] + wsum[2] + wsum[3];
            float inv = 1.f / fmaxf(sqrtf(tot), 1e-12f);
            (ch < C_ ? nqinv : nkinv)[b * C_ + (ch % C_)] = inv;
        }
    }
}

// ---------------- MFMA scores: sp[ks][bh][48][48], ksplit=4, 4 waves/block ----------------
__global__ __launch_bounds__(256) void scores_mfma(
    const _Float16* __restrict__ buf, float* __restrict__ sp)
{
    const int bh = blockIdx.x;
    const int ks = blockIdx.y;
    const int b = bh >> 3, h = bh & 7;
    const _Float16* qbase = buf + ((size_t)b * C3_ + (size_t)h * D_) * HW_;
    const _Float16* kbase = qbase + (size_t)C_ * HW_;
    const int t = threadIdx.x, l = t & 63, w = t >> 6;
    const int frow = l & 15, kseg = (l >> 4) * 8;
    const int p0 = ks * 1024 + w * 256;

    f32x4 acc[3][3] = {};
    #pragma unroll 2
    for (int st = 0; st < 8; ++st) {
        const int p = p0 + st * 32 + kseg;
        f16x8 qf[3], kf[3];
        #pragma unroll
        for (int mi = 0; mi < 3; ++mi)
            qf[mi] = *(const f16x8*)&qbase[(size_t)(mi * 16 + frow) * HW_ + p];
        #pragma unroll
        for (int ni = 0; ni < 3; ++ni)
            kf[ni] = *(const f16x8*)&kbase[(size_t)(ni * 16 + frow) * HW_ + p];
        #pragma unroll
        for (int mi = 0; mi < 3; ++mi)
            #pragma unroll
            for (int ni = 0; ni < 3; ++ni)
                acc[mi][ni] = __builtin_amdgcn_mfma_f32_16x16x32_f16(
                    qf[mi], kf[ni], acc[mi][ni], 0, 0, 0);
    }
    __shared__ float red[4][D_ * D_];
    #pragma unroll
    for (int mi = 0; mi < 3; ++mi)
        #pragma unroll
        for (int ni = 0; ni < 3; ++ni)
            #pragma unroll
            for (int r = 0; r < 4; ++r)
                red[w][(mi * 16 + (l >> 4) * 4 + r) * D_ + ni * 16 + (l & 15)] =
                    acc[mi][ni][r];
    __syncthreads();
    float* out = sp + ((size_t)ks * 128 + bh) * (D_ * D_);
    const float* rf = &red[0][0];
    for (int i = t; i < D_ * D_; i += 256)
        out[i] = rf[i] + rf[2304 + i] + rf[4608 + i] + rf[6912 + i];
}

// ---------------- reduce partials, scale, softmax (4 rows / block) ----------------
__global__ __launch_bounds__(256) void softmax_k(
    const float* __restrict__ sp, const float* __restrict__ nqinv,
    const float* __restrict__ nkinv, const float* __restrict__ temp,
    float* __restrict__ attn)
{
    const int row = blockIdx.x * 4 + (threadIdx.x >> 6);
    const int bh = row / D_, d = row % D_;
    const int h = bh & 7;
    const int e = threadIdx.x & 63;
    float s = -INFINITY;
    if (e < D_) {
        float raw = 0.f;
        #pragma unroll
        for (int ks = 0; ks < 4; ++ks)
            raw += sp[((size_t)ks * 128 + bh) * (D_ * D_) + d * D_ + e];
        s = raw * nqinv[bh * D_ + d] * nkinv[bh * D_ + e] * temp[h];
    }
    float m = s;
    #pragma unroll
    for (int off = 1; off < 64; off <<= 1) m = fmaxf(m, __shfl_xor(m, off));
    float p = (e < D_) ? expf(s - m) : 0.f;
    float sum = p;
    #pragma unroll
    for (int off = 1; off < 64; off <<= 1) sum += __shfl_xor(sum, off);
    if (e < D_) attn[(size_t)bh * (D_ * D_) + d * D_ + e] = p / sum;
}

// ---------------- attn @ v -> fp16 transposed [pixel][384] into q-plane region ----------------
__global__ __launch_bounds__(256) void pv_kernel(
    _Float16* __restrict__ buf, const float* __restrict__ attn)
{
    const int b = blockIdx.z, h = blockIdx.y;
    const int p0 = blockIdx.x * 512 + threadIdx.x * 2;
    __shared__ float a4[48][48];
    const float* ab = attn + ((size_t)b * 8 + h) * (D_ * D_);
    for (int i = threadIdx.x; i < D_ * D_; i += 256) ((float*)a4)[i] = ab[i];
    __syncthreads();
    const _Float16* vbase = buf + ((size_t)b * C3_ + 2 * C_ + (size_t)h * D_) * HW_;
    float2 acc[48];
    #pragma unroll
    for (int d = 0; d < 48; ++d) { acc[d].x = 0.f; acc[d].y = 0.f; }
    #pragma unroll 1
    for (int e4 = 0; e4 < 12; ++e4) {
        float2 vv[4];
        #pragma unroll
        for (int j = 0; j < 4; ++j) {
            f16x2 h2 = *(const f16x2*)&vbase[(size_t)(e4 * 4 + j) * HW_ + p0];
            vv[j].x = (float)h2[0]; vv[j].y = (float)h2[1];
        }
        #pragma unroll
        for (int d = 0; d < 48; ++d) {
            float4 a = *(const float4*)&a4[d][e4 * 4];
            acc[d].x = fmaf(a.x, vv[0].x, fmaf(a.y, vv[1].x, fmaf(a.z, vv[2].x, fmaf(a.w, vv[3].x, acc[d].x))));
            acc[d].y = fmaf(a.x, vv[0].y, fmaf(a.y, vv[1].y, fmaf(a.z, vv[2].y, fmaf(a.w, vv[3].y, acc[d].y))));
        }
    }
    _Float16* xt2b = buf + (size_t)b * C3_ * HW_;   // q region, dead now
    #pragma unroll
    for (int px = 0; px < 2; ++px) {
        f16x8 tmp[6];
        #pragma unroll
        for (int d = 0; d < 48; ++d) tmp[d >> 3][d & 7] = (_Float16)(px ? acc[d].y : acc[d].x);
        f16x8* dst = (f16x8*)&xt2b[(size_t)(p0 + px) * C_ + h * D_];
        #pragma unroll
        for (int j = 0; j < 6; ++j) dst[j] = tmp[j];
    }
}

extern "C" void kernel_launch(void* const* d_in, const int* in_sizes, int n_in,
                              void* d_out, int out_size, void* d_ws, size_t ws_size,
                              hipStream_t stream)
{
    const float* x      = (const float*)d_in[0];
    const float* w_qkv  = (const float*)d_in[1];
    const float* w_dw   = (const float*)d_in[2];
    const float* w_proj = (const float*)d_in[3];
    const float* temp   = (const float*)d_in[4];
    float* out = (float*)d_out;

    _Float16* buf = (_Float16*)d_ws;                       // 16*1152*4096 halves
    float* nqinv = (float*)(buf + (size_t)B_ * C3_ * HW_);
    float* nkinv = nqinv + 6144;
    float* sp    = nkinv + 6144;                           // 4*128*2304 f
    float* attn  = sp + (size_t)4 * 128 * D_ * D_;         // 128*2304 f
    _Float16* wqkv_h  = (_Float16*)(attn + (size_t)128 * D_ * D_);
    _Float16* wproj_h = wqkv_h + (size_t)C3_ * C_;
    _Float16* xt1     = wproj_h + (size_t)C_ * C_;         // 16*4096*384 halves

    // 0) fused input transpose + weight conversion (one launch)
    prep_inputs<<<dim3(64, 6, 17), 256, 0, stream>>>(
        x, xt1, w_qkv, w_proj, wqkv_h, wproj_h);

    // 1) qkv = w_qkv @ x (2-buffer GEMM, 3 blocks/CU, split epilogue, fp16 out)
    mfma_gemm<C3_, false><<<dim3(9 * 16 * 16), 256, 0, stream>>>(
        wqkv_h, xt1, buf, (long long)HW_ * C_, (long long)C3_ * HW_);

    // 2) depthwise 3x3 SAME in place + fused q/k row norms
    dwconv_norm<<<B_ * C3_, 256, 0, stream>>>(buf, w_dw, nqinv, nkinv);

    // 3) raw score partials via MFMA (K split 4)
    scores_mfma<<<dim3(128, 4), 256, 0, stream>>>(buf, sp);

    // 4) reduce + scale + softmax
    softmax_k<<<1536, 256, 0, stream>>>(sp, nqinv, nkinv, temp, attn);

    // 5) attn @ v (VALU, validated) -> fp16 transposed into q region
    pv_kernel<<<dim3(8, 8, 16), 256, 0, stream>>>(buf, attn);

    // 6) out = w_proj @ attn_out (2-buffer GEMM, split epilogue, fp32 out)
    mfma_gemm<C_, true><<<dim3(3 * 16 * 16), 256, 0, stream>>>(
        wproj_h, buf, out, (long long)C3_ * HW_, (long long)C_ * HW_);
}

// Round 22
// 264.394 us; speedup vs baseline: 1.1030x; 1.1030x over previous
//
#include <hip/hip_runtime.h>
#include <hip/hip_bf16.h>
#include <math.h>

#define B_   16
#define C_   384
#define C3_  1152
#define HW_  4096
#define NH_  8
#define D_   48

typedef _Float16 f16x8 __attribute__((ext_vector_type(8)));
typedef _Float16 f16x4 __attribute__((ext_vector_type(4)));
typedef _Float16 f16x2 __attribute__((ext_vector_type(2)));
typedef float    f32x4 __attribute__((ext_vector_type(4)));

#define ASM_VMCNT(n) asm volatile("s_waitcnt vmcnt(" #n ")" ::: "memory")

// ---------------- fused: x transpose->fp16 (z<16) + weight conversion (z==16) ----------------
__global__ __launch_bounds__(256) void prep_inputs(
    const float* __restrict__ x, _Float16* __restrict__ xt,
    const float* __restrict__ wqkv, const float* __restrict__ wproj,
    _Float16* __restrict__ oq, _Float16* __restrict__ op)
{
    const int t = threadIdx.x;
    if (blockIdx.z == 16) {               // weight conversion: 384 blocks x 256 thr
        const int nq = C3_ * C_ / 4;      // float4 units
        const int np = C_ * C_ / 4;
        int idx = (blockIdx.y * 64 + blockIdx.x) * 256 + t;
        for (int i = idx; i < nq + np; i += 384 * 256) {
            const float* src; _Float16* dst; int j;
            if (i < nq) { src = wqkv; dst = oq; j = i; }
            else        { src = wproj; dst = op; j = i - nq; }
            float4 v = *(const float4*)&src[(size_t)j * 4];
            f16x4 h = { (_Float16)v.x, (_Float16)v.y, (_Float16)v.z, (_Float16)v.w };
            *(f16x4*)&dst[(size_t)j * 4] = h;
        }
        return;
    }
    const int b  = blockIdx.z;
    const int k0 = blockIdx.y * 64;
    const int n0 = blockIdx.x * 64;
    __shared__ float sm[64][65];
    const float* xb = x + (size_t)b * C_ * HW_;
    _Float16* xtb = xt + (size_t)b * HW_ * C_;
    #pragma unroll
    for (int i = 0; i < 4; ++i) {
        int row = (t >> 4) + i * 16;
        int col = (t & 15) * 4;
        float4 v = *(const float4*)&xb[(size_t)(k0 + row) * HW_ + n0 + col];
        sm[row][col] = v.x; sm[row][col+1] = v.y; sm[row][col+2] = v.z; sm[row][col+3] = v.w;
    }
    __syncthreads();
    #pragma unroll
    for (int i = 0; i < 2; ++i) {
        int nl = (t >> 3) + i * 32;
        int ks = (t & 7) * 8;
        f16x8 h;
        #pragma unroll
        for (int j = 0; j < 8; ++j) h[j] = (_Float16)sm[ks + j][nl];
        *(f16x8*)&xtb[(size_t)(n0 + nl) * C_ + k0 + ks] = h;
    }
}

// ---------------- MFMA GEMM: 128x256 tile, BK=32, 3 buffers, counted vmcnt(6),
// one barrier/K-step, phased inner loop, coalesced LDS-transpose epilogue ----------------
template<int M, bool F32OUT>
__global__ __launch_bounds__(256, 2) void mfma_gemm(
    const _Float16* __restrict__ Wb,
    const _Float16* __restrict__ XT,
    void* __restrict__ Cv, long long xstride, long long cstride)
{
    constexpr int K = 384;
    constexpr int BK = 32;
    constexpr int NSTEP = K / BK;            // 12
    constexpr int MB = M / 128;              // 9 or 3
    __shared__ _Float16 LDS[36864];          // 72 KB: staging, then epilogue transpose
    _Float16* Ash = LDS;                     // [3][128*32]
    _Float16* Bsh = LDS + 3 * 128 * BK;      // [3][256*32]

    // bijective XCD swizzle; logical order: m fastest, then n, then b
    const int nwg = MB * 16 * B_;
    const int cpx = nwg >> 3;
    const int bid = blockIdx.x;
    const int L   = (bid & 7) * cpx + (bid >> 3);
    const int m0  = (L % MB) * 128;
    const int nb  = L / MB;
    const int n0  = (nb & 15) * 256;
    const int b   = nb >> 4;

    const _Float16* __restrict__ XTb = XT + (size_t)b * xstride;
    const int t = threadIdx.x;
    const int l = t & 63, w = t >> 6;
    const int frow = l & 15, kseg16 = l >> 4;

    auto stage = [&](int d, int kt) {
        const int kk = kt * BK;
        #pragma unroll
        for (int i = 0; i < 2; ++i) {            // A: 128 rows x 32 k = 8 KB
            const int u = i * 256 + t;
            const int row = u >> 2, slot = u & 3;
            const int scol = slot ^ (row & 3) ^ ((row >> 2) & 1);
            const _Float16* ga = Wb + (size_t)(m0 + row) * K + kk + scol * 8;
            __builtin_amdgcn_global_load_lds(
                (const __attribute__((address_space(1))) void*)ga,
                (__attribute__((address_space(3))) void*)((char*)(Ash + d * 128 * BK) + u * 16),
                16, 0, 0);
        }
        #pragma unroll
        for (int i = 0; i < 4; ++i) {            // B: 256 rows x 32 k = 16 KB
            const int u = i * 256 + t;
            const int row = u >> 2, slot = u & 3;
            const int scol = slot ^ (row & 3) ^ ((row >> 2) & 1);
            const _Float16* gb = XTb + (size_t)(n0 + row) * K + kk + scol * 8;
            __builtin_amdgcn_global_load_lds(
                (const __attribute__((address_space(1))) void*)gb,
                (__attribute__((address_space(3))) void*)((char*)(Bsh + d * 256 * BK) + u * 16),
                16, 0, 0);
        }
    };

    f32x4 acc[8][4] = {};

    stage(0, 0); stage(1, 1);                    // 12 loads outstanding
    #pragma unroll
    for (int kt = 0; kt < NSTEP; ++kt) {
        const int cur = kt % 3;
        if (kt + 1 < NSTEP) { ASM_VMCNT(6); } else { ASM_VMCNT(0); }
        __builtin_amdgcn_sched_barrier(0);
        __builtin_amdgcn_s_barrier();            // tile kt visible; prev reads done
        __builtin_amdgcn_sched_barrier(0);
        if (kt + 2 < NSTEP) stage((kt + 2) % 3, kt + 2);

        const _Float16* Abase = &Ash[cur * 128 * BK];
        const _Float16* Bbase = &Bsh[cur * 256 * BK];

        f16x8 bfr[4];
        #pragma unroll
        for (int ni = 0; ni < 4; ++ni) {
            const int rB = w * 64 + ni * 16 + frow;
            const int cs = kseg16 ^ (rB & 3) ^ ((rB >> 2) & 1);
            bfr[ni] = *(const f16x8*)&Bbase[rB * BK + cs * 8];
        }
        f16x8 afb[2];
        {
            const int rA = frow;
            const int cs = kseg16 ^ (rA & 3) ^ ((rA >> 2) & 1);
            afb[0] = *(const f16x8*)&Abase[rA * BK + cs * 8];
        }
        __builtin_amdgcn_sched_group_barrier(0x100, 5, 0);   // 5 DS_READ (prologue)
        __builtin_amdgcn_s_setprio(1);
        #pragma unroll
        for (int mi = 0; mi < 8; ++mi) {
            if (mi + 1 < 8) {
                const int rA = (mi + 1) * 16 + frow;
                const int cs = kseg16 ^ (rA & 3) ^ ((rA >> 2) & 1);
                afb[(mi + 1) & 1] = *(const f16x8*)&Abase[rA * BK + cs * 8];
            }
            #pragma unroll
            for (int ni = 0; ni < 4; ++ni)
                acc[mi][ni] = __builtin_amdgcn_mfma_f32_16x16x32_f16(
                    bfr[ni], afb[mi & 1], acc[mi][ni], 0, 0, 0);   // D[pixel][channel]
            if (mi + 1 < 8)
                __builtin_amdgcn_sched_group_barrier(0x100, 1, 0); // 1 DS_READ
            __builtin_amdgcn_sched_group_barrier(0x008, 4, 0);     // 4 MFMA
        }
        __builtin_amdgcn_s_setprio(0);
    }

    // ---- coalesced epilogue: per-wave LDS transpose (wave-local, no extra barrier) ----
    __syncthreads();                             // staging LDS dead across all waves
    char* tbase = (char*)LDS + w * 17408;        // 4 x 17408 = 69632 <= 73728
    if constexpr (!F32OUT) {
        #pragma unroll
        for (int mi = 0; mi < 8; ++mi)
            #pragma unroll
            for (int ni = 0; ni < 4; ++ni) {
                const int row = mi * 16 + (l & 15);
                const int pxl = ni * 16 + (l >> 4) * 4;
                f16x2 lo = { (_Float16)acc[mi][ni][0], (_Float16)acc[mi][ni][1] };
                f16x2 hi = { (_Float16)acc[mi][ni][2], (_Float16)acc[mi][ni][3] };
                *(f16x2*)(tbase + row * 136 + pxl * 2)     = lo;
                *(f16x2*)(tbase + row * 136 + pxl * 2 + 4) = hi;
            }
        asm volatile("s_waitcnt lgkmcnt(0)" ::: "memory");
        __builtin_amdgcn_sched_barrier(0);
        _Float16* Co = (_Float16*)Cv + (size_t)b * cstride;
        #pragma unroll
        for (int j = 0; j < 16; ++j) {
            const int ch = j * 8 + (l >> 3);
            const int px = (l & 7) * 8;
            f16x4 lo = *(const f16x4*)(tbase + ch * 136 + px * 2);
            f16x4 hi = *(const f16x4*)(tbase + ch * 136 + px * 2 + 8);
            f16x8 v;
            #pragma unroll
            for (int q = 0; q < 4; ++q) { v[q] = lo[q]; v[q + 4] = hi[q]; }
            *(f16x8*)&Co[(size_t)(m0 + ch) * HW_ + n0 + w * 64 + px] = v;
        }
    } else {
        float* Co = (float*)Cv + (size_t)b * cstride;
        #pragma unroll
        for (int p = 0; p < 2; ++p) {
            if (p) { asm volatile("s_waitcnt lgkmcnt(0)" ::: "memory");
                     __builtin_amdgcn_sched_barrier(0); }
            #pragma unroll
            for (int mi = 0; mi < 4; ++mi)
                #pragma unroll
                for (int ni = 0; ni < 4; ++ni) {
                    const int row = mi * 16 + (l & 15);
                    const int pxl = ni * 16 + (l >> 4) * 4;
                    float2 lo = make_float2(acc[p * 4 + mi][ni][0], acc[p * 4 + mi][ni][1]);
                    float2 hi = make_float2(acc[p * 4 + mi][ni][2], acc[p * 4 + mi][ni][3]);
                    *(float2*)(tbase + row * 272 + pxl * 4)     = lo;
                    *(float2*)(tbase + row * 272 + pxl * 4 + 8) = hi;
                }
            asm volatile("s_waitcnt lgkmcnt(0)" ::: "memory");
            __builtin_amdgcn_sched_barrier(0);
            #pragma unroll
            for (int j = 0; j < 16; ++j) {
                const int lch = j * 4 + (l >> 4);
                const int ch  = p * 64 + lch;
                const int px  = (l & 15) * 4;
                float2 lo = *(const float2*)(tbase + lch * 272 + px * 4);
                float2 hi = *(const float2*)(tbase + lch * 272 + px * 4 + 8);
                f32x4 v = { lo.x, lo.y, hi.x, hi.y };
                *(f32x4*)&Co[(size_t)(m0 + ch) * HW_ + n0 + w * 64 + px] = v;
            }
        }
    }
}

// ---------------- depthwise 3x3 SAME in-place (fp16) + fused q/k row-norms ----------------
__global__ __launch_bounds__(256) void dwconv_norm(
    _Float16* __restrict__ buf, const float* __restrict__ wdw,
    float* __restrict__ nqinv, float* __restrict__ nkinv)
{
    const int plane = blockIdx.x;
    const int ch = plane % C3_, b = plane / C3_;
    __shared__ _Float16 smh[64 * 72];
    __shared__ float wsum[4];
    _Float16* g = buf + (size_t)plane * HW_;
    const int t = threadIdx.x;
    #pragma unroll
    for (int i = 0; i < 2; ++i) {
        const int u = i * 256 + t;
        f16x8 v = *(const f16x8*)&g[u * 8];
        *(f16x8*)&smh[(u >> 3) * 72 + (u & 7) * 8] = v;
    }
    float w[9];
    #pragma unroll
    for (int j = 0; j < 9; ++j) w[j] = wdw[ch * 9 + j];
    __syncthreads();
    float ssq = 0.f;
    #pragma unroll
    for (int i = 0; i < 2; ++i) {
        const int u = i * 256 + t;
        const int y = u >> 3, c0 = (u & 7) * 8;
        float r[3][10];
        #pragma unroll
        for (int dy = 0; dy < 3; ++dy) {
            const int yy = y + dy - 1;
            if (yy < 0 || yy > 63) {
                #pragma unroll
                for (int j = 0; j < 10; ++j) r[dy][j] = 0.f;
            } else {
                f16x8 v = *(const f16x8*)&smh[yy * 72 + c0];
                #pragma unroll
                for (int j = 0; j < 8; ++j) r[dy][j + 1] = (float)v[j];
                r[dy][0] = (c0 > 0)  ? (float)smh[yy * 72 + c0 - 1] : 0.f;
                r[dy][9] = (c0 < 56) ? (float)smh[yy * 72 + c0 + 8] : 0.f;
            }
        }
        f16x8 o;
        #pragma unroll
        for (int j = 0; j < 8; ++j) {
            float s = 0.f;
            #pragma unroll
            for (int dy = 0; dy < 3; ++dy)
                #pragma unroll
                for (int dx = 0; dx < 3; ++dx)
                    s = fmaf(w[dy * 3 + dx], r[dy][j + dx], s);
            o[j] = (_Float16)s;
            ssq = fmaf(s, s, ssq);
        }
        *(f16x8*)&g[u * 8] = o;
    }
    if (ch < 2 * C_) {
        #pragma unroll
        for (int m = 1; m < 64; m <<= 1) ssq += __shfl_xor(ssq, m);
        if ((t & 63) == 0) wsum[t >> 6] = ssq;
        __syncthreads();
        if (t == 0) {
            float tot = wsum[0] + wsum[1] + wsum[2] + wsum[3];
            float inv = 1.f / fmaxf(sqrtf(tot), 1e-12f);
            (ch < C_ ? nqinv : nkinv)[b * C_ + (ch % C_)] = inv;
        }
    }
}

// ---------------- MFMA scores: sp[ks][bh][48][48], ksplit=4, 4 waves/block ----------------
__global__ __launch_bounds__(256) void scores_mfma(
    const _Float16* __restrict__ buf, float* __restrict__ sp)
{
    const int bh = blockIdx.x;
    const int ks = blockIdx.y;
    const int b = bh >> 3, h = bh & 7;
    const _Float16* qbase = buf + ((size_t)b * C3_ + (size_t)h * D_) * HW_;
    const _Float16* kbase = qbase + (size_t)C_ * HW_;
    const int t = threadIdx.x, l = t & 63, w = t >> 6;
    const int frow = l & 15, kseg = (l >> 4) * 8;
    const int p0 = ks * 1024 + w * 256;

    f32x4 acc[3][3] = {};
    #pragma unroll 2
    for (int st = 0; st < 8; ++st) {
        const int p = p0 + st * 32 + kseg;
        f16x8 qf[3], kf[3];
        #pragma unroll
        for (int mi = 0; mi < 3; ++mi)
            qf[mi] = *(const f16x8*)&qbase[(size_t)(mi * 16 + frow) * HW_ + p];
        #pragma unroll
        for (int ni = 0; ni < 3; ++ni)
            kf[ni] = *(const f16x8*)&kbase[(size_t)(ni * 16 + frow) * HW_ + p];
        #pragma unroll
        for (int mi = 0; mi < 3; ++mi)
            #pragma unroll
            for (int ni = 0; ni < 3; ++ni)
                acc[mi][ni] = __builtin_amdgcn_mfma_f32_16x16x32_f16(
                    qf[mi], kf[ni], acc[mi][ni], 0, 0, 0);
    }
    __shared__ float red[4][D_ * D_];
    #pragma unroll
    for (int mi = 0; mi < 3; ++mi)
        #pragma unroll
        for (int ni = 0; ni < 3; ++ni)
            #pragma unroll
            for (int r = 0; r < 4; ++r)
                red[w][(mi * 16 + (l >> 4) * 4 + r) * D_ + ni * 16 + (l & 15)] =
                    acc[mi][ni][r];
    __syncthreads();
    float* out = sp + ((size_t)ks * 128 + bh) * (D_ * D_);
    const float* rf = &red[0][0];
    for (int i = t; i < D_ * D_; i += 256)
        out[i] = rf[i] + rf[2304 + i] + rf[4608 + i] + rf[6912 + i];
}

// ---------------- reduce partials, scale, softmax (4 rows / block) ----------------
__global__ __launch_bounds__(256) void softmax_k(
    const float* __restrict__ sp, const float* __restrict__ nqinv,
    const float* __restrict__ nkinv, const float* __restrict__ temp,
    float* __restrict__ attn)
{
    const int row = blockIdx.x * 4 + (threadIdx.x >> 6);
    const int bh = row / D_, d = row % D_;
    const int h = bh & 7;
    const int e = threadIdx.x & 63;
    float s = -INFINITY;
    if (e < D_) {
        float raw = 0.f;
        #pragma unroll
        for (int ks = 0; ks < 4; ++ks)
            raw += sp[((size_t)ks * 128 + bh) * (D_ * D_) + d * D_ + e];
        s = raw * nqinv[bh * D_ + d] * nkinv[bh * D_ + e] * temp[h];
    }
    float m = s;
    #pragma unroll
    for (int off = 1; off < 64; off <<= 1) m = fmaxf(m, __shfl_xor(m, off));
    float p = (e < D_) ? expf(s - m) : 0.f;
    float sum = p;
    #pragma unroll
    for (int off = 1; off < 64; off <<= 1) sum += __shfl_xor(sum, off);
    if (e < D_) attn[(size_t)bh * (D_ * D_) + d * D_ + e] = p / sum;
}

// ---------------- attn @ v -> fp16 transposed [pixel][384] into q-plane region ----------------
__global__ __launch_bounds__(256) void pv_kernel(
    _Float16* __restrict__ buf, const float* __restrict__ attn)
{
    const int b = blockIdx.z, h = blockIdx.y;
    const int p0 = blockIdx.x * 512 + threadIdx.x * 2;
    __shared__ float a4[48][48];
    const float* ab = attn + ((size_t)b * 8 + h) * (D_ * D_);
    for (int i = threadIdx.x; i < D_ * D_; i += 256) ((float*)a4)[i] = ab[i];
    __syncthreads();
    const _Float16* vbase = buf + ((size_t)b * C3_ + 2 * C_ + (size_t)h * D_) * HW_;
    float2 acc[48];
    #pragma unroll
    for (int d = 0; d < 48; ++d) { acc[d].x = 0.f; acc[d].y = 0.f; }
    #pragma unroll 1
    for (int e4 = 0; e4 < 12; ++e4) {
        float2 vv[4];
        #pragma unroll
        for (int j = 0; j < 4; ++j) {
            f16x2 h2 = *(const f16x2*)&vbase[(size_t)(e4 * 4 + j) * HW_ + p0];
            vv[j].x = (float)h2[0]; vv[j].y = (float)h2[1];
        }
        #pragma unroll
        for (int d = 0; d < 48; ++d) {
            float4 a = *(const float4*)&a4[d][e4 * 4];
            acc[d].x = fmaf(a.x, vv[0].x, fmaf(a.y, vv[1].x, fmaf(a.z, vv[2].x, fmaf(a.w, vv[3].x, acc[d].x))));
            acc[d].y = fmaf(a.x, vv[0].y, fmaf(a.y, vv[1].y, fmaf(a.z, vv[2].y, fmaf(a.w, vv[3].y, acc[d].y))));
        }
    }
    _Float16* xt2b = buf + (size_t)b * C3_ * HW_;   // q region, dead now
    #pragma unroll
    for (int px = 0; px < 2; ++px) {
        f16x8 tmp[6];
        #pragma unroll
        for (int d = 0; d < 48; ++d) tmp[d >> 3][d & 7] = (_Float16)(px ? acc[d].y : acc[d].x);
        f16x8* dst = (f16x8*)&xt2b[(size_t)(p0 + px) * C_ + h * D_];
        #pragma unroll
        for (int j = 0; j < 6; ++j) dst[j] = tmp[j];
    }
}

extern "C" void kernel_launch(void* const* d_in, const int* in_sizes, int n_in,
                              void* d_out, int out_size, void* d_ws, size_t ws_size,
                              hipStream_t stream)
{
    const float* x      = (const float*)d_in[0];
    const float* w_qkv  = (const float*)d_in[1];
    const float* w_dw   = (const float*)d_in[2];
    const float* w_proj = (const float*)d_in[3];
    const float* temp   = (const float*)d_in[4];
    float* out = (float*)d_out;

    _Float16* buf = (_Float16*)d_ws;                       // 16*1152*4096 halves
    float* nqinv = (float*)(buf + (size_t)B_ * C3_ * HW_);
    float* nkinv = nqinv + 6144;
    float* sp    = nkinv + 6144;                           // 4*128*2304 f
    float* attn  = sp + (size_t)4 * 128 * D_ * D_;         // 128*2304 f
    _Float16* wqkv_h  = (_Float16*)(attn + (size_t)128 * D_ * D_);
    _Float16* wproj_h = wqkv_h + (size_t)C3_ * C_;
    _Float16* xt1     = wproj_h + (size_t)C_ * C_;         // 16*4096*384 halves

    // 0) fused input transpose + weight conversion (one launch)
    prep_inputs<<<dim3(64, 6, 17), 256, 0, stream>>>(
        x, xt1, w_qkv, w_proj, wqkv_h, wproj_h);

    // 1) qkv = w_qkv @ x (GEMM + coalesced epilogue, fp16 out)
    mfma_gemm<C3_, false><<<dim3(9 * 16 * 16), 256, 0, stream>>>(
        wqkv_h, xt1, buf, (long long)HW_ * C_, (long long)C3_ * HW_);

    // 2) depthwise 3x3 SAME in place + fused q/k row norms
    dwconv_norm<<<B_ * C3_, 256, 0, stream>>>(buf, w_dw, nqinv, nkinv);

    // 3) raw score partials via MFMA (K split 4)
    scores_mfma<<<dim3(128, 4), 256, 0, stream>>>(buf, sp);

    // 4) reduce + scale + softmax
    softmax_k<<<1536, 256, 0, stream>>>(sp, nqinv, nkinv, temp, attn);

    // 5) attn @ v (VALU, validated) -> fp16 transposed into q region
    pv_kernel<<<dim3(8, 8, 16), 256, 0, stream>>>(buf, attn);

    // 6) out = w_proj @ attn_out (GEMM + coalesced epilogue, fp32 out)
    mfma_gemm<C_, true><<<dim3(3 * 16 * 16), 256, 0, stream>>>(
        wproj_h, buf, out, (long long)C3_ * HW_, (long long)C_ * HW_);
}

// Round 23
// 261.756 us; speedup vs baseline: 1.1141x; 1.0101x over previous
//
#include <hip/hip_runtime.h>
#include <hip/hip_bf16.h>
#include <math.h>

#define B_   16
#define C_   384
#define C3_  1152
#define HW_  4096
#define NH_  8
#define D_   48

typedef _Float16 f16x8 __attribute__((ext_vector_type(8)));
typedef _Float16 f16x4 __attribute__((ext_vector_type(4)));
typedef _Float16 f16x2 __attribute__((ext_vector_type(2)));
typedef float    f32x4 __attribute__((ext_vector_type(4)));

#define ASM_VMCNT(n) asm volatile("s_waitcnt vmcnt(" #n ")" ::: "memory")

// ---------------- fused: x transpose->fp16 (z<16) + weight conversion (z==16) ----------------
__global__ __launch_bounds__(256) void prep_inputs(
    const float* __restrict__ x, _Float16* __restrict__ xt,
    const float* __restrict__ wqkv, const float* __restrict__ wproj,
    _Float16* __restrict__ oq, _Float16* __restrict__ op)
{
    const int t = threadIdx.x;
    if (blockIdx.z == 16) {               // weight conversion: 384 blocks x 256 thr
        const int nq = C3_ * C_ / 4;      // float4 units
        const int np = C_ * C_ / 4;
        int idx = (blockIdx.y * 64 + blockIdx.x) * 256 + t;
        for (int i = idx; i < nq + np; i += 384 * 256) {
            const float* src; _Float16* dst; int j;
            if (i < nq) { src = wqkv; dst = oq; j = i; }
            else        { src = wproj; dst = op; j = i - nq; }
            float4 v = *(const float4*)&src[(size_t)j * 4];
            f16x4 h = { (_Float16)v.x, (_Float16)v.y, (_Float16)v.z, (_Float16)v.w };
            *(f16x4*)&dst[(size_t)j * 4] = h;
        }
        return;
    }
    const int b  = blockIdx.z;
    const int k0 = blockIdx.y * 64;
    const int n0 = blockIdx.x * 64;
    __shared__ float sm[64][65];
    const float* xb = x + (size_t)b * C_ * HW_;
    _Float16* xtb = xt + (size_t)b * HW_ * C_;
    #pragma unroll
    for (int i = 0; i < 4; ++i) {
        int row = (t >> 4) + i * 16;
        int col = (t & 15) * 4;
        float4 v = *(const float4*)&xb[(size_t)(k0 + row) * HW_ + n0 + col];
        sm[row][col] = v.x; sm[row][col+1] = v.y; sm[row][col+2] = v.z; sm[row][col+3] = v.w;
    }
    __syncthreads();
    #pragma unroll
    for (int i = 0; i < 2; ++i) {
        int nl = (t >> 3) + i * 32;
        int ks = (t & 7) * 8;
        f16x8 h;
        #pragma unroll
        for (int j = 0; j < 8; ++j) h[j] = (_Float16)sm[ks + j][nl];
        *(f16x8*)&xtb[(size_t)(n0 + nl) * C_ + k0 + ks] = h;
    }
}

// ---------------- MFMA GEMM: 128x256 tile, BK=32, 3 buffers, counted vmcnt(6),
// one barrier/K-step, phased inner loop with PER-PHASE G-load issue (1 VMEM +
// 1 DS_READ + 4 MFMA per phase), coalesced LDS-transpose epilogue ----------------
template<int M, bool F32OUT>
__global__ __launch_bounds__(256, 2) void mfma_gemm(
    const _Float16* __restrict__ Wb,
    const _Float16* __restrict__ XT,
    void* __restrict__ Cv, long long xstride, long long cstride)
{
    constexpr int K = 384;
    constexpr int BK = 32;
    constexpr int NSTEP = K / BK;            // 12
    constexpr int MB = M / 128;              // 9 or 3
    __shared__ _Float16 LDS[36864];          // 72 KB: staging, then epilogue transpose
    _Float16* Ash = LDS;                     // [3][128*32]
    _Float16* Bsh = LDS + 3 * 128 * BK;      // [3][256*32]

    // bijective XCD swizzle; logical order: m fastest, then n, then b
    const int nwg = MB * 16 * B_;
    const int cpx = nwg >> 3;
    const int bid = blockIdx.x;
    const int L   = (bid & 7) * cpx + (bid >> 3);
    const int m0  = (L % MB) * 128;
    const int nb  = L / MB;
    const int n0  = (nb & 15) * 256;
    const int b   = nb >> 4;

    const _Float16* __restrict__ XTb = XT + (size_t)b * xstride;
    const int t = threadIdx.x;
    const int l = t & 63, w = t >> 6;
    const int frow = l & 15, kseg16 = l >> 4;

    // one 16-B global_load_lds; part i of 6 (0-1: A halves, 2-5: B quarters)
    auto stage_part = [&](int d, int kt, int i) {
        const int kk = kt * BK;
        if (i < 2) {
            const int u = i * 256 + t;
            const int row = u >> 2, slot = u & 3;
            const int scol = slot ^ (row & 3) ^ ((row >> 2) & 1);
            const _Float16* ga = Wb + (size_t)(m0 + row) * K + kk + scol * 8;
            __builtin_amdgcn_global_load_lds(
                (const __attribute__((address_space(1))) void*)ga,
                (__attribute__((address_space(3))) void*)((char*)(Ash + d * 128 * BK) + u * 16),
                16, 0, 0);
        } else {
            const int u = (i - 2) * 256 + t;
            const int row = u >> 2, slot = u & 3;
            const int scol = slot ^ (row & 3) ^ ((row >> 2) & 1);
            const _Float16* gb = XTb + (size_t)(n0 + row) * K + kk + scol * 8;
            __builtin_amdgcn_global_load_lds(
                (const __attribute__((address_space(1))) void*)gb,
                (__attribute__((address_space(3))) void*)((char*)(Bsh + d * 256 * BK) + u * 16),
                16, 0, 0);
        }
    };
    auto stage_all = [&](int d, int kt) {
        #pragma unroll
        for (int i = 0; i < 6; ++i) stage_part(d, kt, i);
    };

    f32x4 acc[8][4] = {};

    stage_all(0, 0); stage_all(1, 1);            // 12 loads outstanding
    #pragma unroll
    for (int kt = 0; kt < NSTEP; ++kt) {
        const int cur = kt % 3;
        const bool do_stage = (kt + 2 < NSTEP);
        if (kt + 1 < NSTEP) { ASM_VMCNT(6); } else { ASM_VMCNT(0); }
        __builtin_amdgcn_sched_barrier(0);
        __builtin_amdgcn_s_barrier();            // tile kt visible; prev reads done
        __builtin_amdgcn_sched_barrier(0);

        const _Float16* Abase = &Ash[cur * 128 * BK];
        const _Float16* Bbase = &Bsh[cur * 256 * BK];

        f16x8 bfr[4];
        #pragma unroll
        for (int ni = 0; ni < 4; ++ni) {
            const int rB = w * 64 + ni * 16 + frow;
            const int cs = kseg16 ^ (rB & 3) ^ ((rB >> 2) & 1);
            bfr[ni] = *(const f16x8*)&Bbase[rB * BK + cs * 8];
        }
        f16x8 afb[2];
        {
            const int rA = frow;
            const int cs = kseg16 ^ (rA & 3) ^ ((rA >> 2) & 1);
            afb[0] = *(const f16x8*)&Abase[rA * BK + cs * 8];
        }
        __builtin_amdgcn_sched_group_barrier(0x100, 5, 0);   // 5 DS_READ (prologue)
        __builtin_amdgcn_s_setprio(1);
        // 8 phases: 1 G-load (phases 0-5) || 1 A-frag ds_read || 4 MFMAs
        #pragma unroll
        for (int mi = 0; mi < 8; ++mi) {
            if (do_stage && mi < 6)
                stage_part((kt + 2) % 3, kt + 2, mi);
            if (mi + 1 < 8) {
                const int rA = (mi + 1) * 16 + frow;
                const int cs = kseg16 ^ (rA & 3) ^ ((rA >> 2) & 1);
                afb[(mi + 1) & 1] = *(const f16x8*)&Abase[rA * BK + cs * 8];
            }
            #pragma unroll
            for (int ni = 0; ni < 4; ++ni)
                acc[mi][ni] = __builtin_amdgcn_mfma_f32_16x16x32_f16(
                    bfr[ni], afb[mi & 1], acc[mi][ni], 0, 0, 0);   // D[pixel][channel]
            if (do_stage && mi < 6)
                __builtin_amdgcn_sched_group_barrier(0x020, 1, 0); // 1 VMEM_READ
            if (mi + 1 < 8)
                __builtin_amdgcn_sched_group_barrier(0x100, 1, 0); // 1 DS_READ
            __builtin_amdgcn_sched_group_barrier(0x008, 4, 0);     // 4 MFMA
        }
        __builtin_amdgcn_s_setprio(0);
    }

    // ---- coalesced epilogue: per-wave LDS transpose (wave-local, no extra barrier) ----
    __syncthreads();                             // staging LDS dead across all waves
    char* tbase = (char*)LDS + w * 17408;        // 4 x 17408 = 69632 <= 73728
    if constexpr (!F32OUT) {
        #pragma unroll
        for (int mi = 0; mi < 8; ++mi)
            #pragma unroll
            for (int ni = 0; ni < 4; ++ni) {
                const int row = mi * 16 + (l & 15);
                const int pxl = ni * 16 + (l >> 4) * 4;
                f16x2 lo = { (_Float16)acc[mi][ni][0], (_Float16)acc[mi][ni][1] };
                f16x2 hi = { (_Float16)acc[mi][ni][2], (_Float16)acc[mi][ni][3] };
                *(f16x2*)(tbase + row * 136 + pxl * 2)     = lo;
                *(f16x2*)(tbase + row * 136 + pxl * 2 + 4) = hi;
            }
        asm volatile("s_waitcnt lgkmcnt(0)" ::: "memory");
        __builtin_amdgcn_sched_barrier(0);
        _Float16* Co = (_Float16*)Cv + (size_t)b * cstride;
        #pragma unroll
        for (int j = 0; j < 16; ++j) {
            const int ch = j * 8 + (l >> 3);
            const int px = (l & 7) * 8;
            f16x4 lo = *(const f16x4*)(tbase + ch * 136 + px * 2);
            f16x4 hi = *(const f16x4*)(tbase + ch * 136 + px * 2 + 8);
            f16x8 v;
            #pragma unroll
            for (int q = 0; q < 4; ++q) { v[q] = lo[q]; v[q + 4] = hi[q]; }
            *(f16x8*)&Co[(size_t)(m0 + ch) * HW_ + n0 + w * 64 + px] = v;
        }
    } else {
        float* Co = (float*)Cv + (size_t)b * cstride;
        #pragma unroll
        for (int p = 0; p < 2; ++p) {
            if (p) { asm volatile("s_waitcnt lgkmcnt(0)" ::: "memory");
                     __builtin_amdgcn_sched_barrier(0); }
            #pragma unroll
            for (int mi = 0; mi < 4; ++mi)
                #pragma unroll
                for (int ni = 0; ni < 4; ++ni) {
                    const int row = mi * 16 + (l & 15);
                    const int pxl = ni * 16 + (l >> 4) * 4;
                    float2 lo = make_float2(acc[p * 4 + mi][ni][0], acc[p * 4 + mi][ni][1]);
                    float2 hi = make_float2(acc[p * 4 + mi][ni][2], acc[p * 4 + mi][ni][3]);
                    *(float2*)(tbase + row * 272 + pxl * 4)     = lo;
                    *(float2*)(tbase + row * 272 + pxl * 4 + 8) = hi;
                }
            asm volatile("s_waitcnt lgkmcnt(0)" ::: "memory");
            __builtin_amdgcn_sched_barrier(0);
            #pragma unroll
            for (int j = 0; j < 16; ++j) {
                const int lch = j * 4 + (l >> 4);
                const int ch  = p * 64 + lch;
                const int px  = (l & 15) * 4;
                float2 lo = *(const float2*)(tbase + lch * 272 + px * 4);
                float2 hi = *(const float2*)(tbase + lch * 272 + px * 4 + 8);
                f32x4 v = { lo.x, lo.y, hi.x, hi.y };
                *(f32x4*)&Co[(size_t)(m0 + ch) * HW_ + n0 + w * 64 + px] = v;
            }
        }
    }
}

// ---------------- depthwise 3x3 SAME in-place (fp16) + fused q/k row-norms ----------------
__global__ __launch_bounds__(256) void dwconv_norm(
    _Float16* __restrict__ buf, const float* __restrict__ wdw,
    float* __restrict__ nqinv, float* __restrict__ nkinv)
{
    const int plane = blockIdx.x;
    const int ch = plane % C3_, b = plane / C3_;
    __shared__ _Float16 smh[64 * 72];
    __shared__ float wsum[4];
    _Float16* g = buf + (size_t)plane * HW_;
    const int t = threadIdx.x;
    #pragma unroll
    for (int i = 0; i < 2; ++i) {
        const int u = i * 256 + t;
        f16x8 v = *(const f16x8*)&g[u * 8];
        *(f16x8*)&smh[(u >> 3) * 72 + (u & 7) * 8] = v;
    }
    float w[9];
    #pragma unroll
    for (int j = 0; j < 9; ++j) w[j] = wdw[ch * 9 + j];
    __syncthreads();
    float ssq = 0.f;
    #pragma unroll
    for (int i = 0; i < 2; ++i) {
        const int u = i * 256 + t;
        const int y = u >> 3, c0 = (u & 7) * 8;
        float r[3][10];
        #pragma unroll
        for (int dy = 0; dy < 3; ++dy) {
            const int yy = y + dy - 1;
            if (yy < 0 || yy > 63) {
                #pragma unroll
                for (int j = 0; j < 10; ++j) r[dy][j] = 0.f;
            } else {
                f16x8 v = *(const f16x8*)&smh[yy * 72 + c0];
                #pragma unroll
                for (int j = 0; j < 8; ++j) r[dy][j + 1] = (float)v[j];
                r[dy][0] = (c0 > 0)  ? (float)smh[yy * 72 + c0 - 1] : 0.f;
                r[dy][9] = (c0 < 56) ? (float)smh[yy * 72 + c0 + 8] : 0.f;
            }
        }
        f16x8 o;
        #pragma unroll
        for (int j = 0; j < 8; ++j) {
            float s = 0.f;
            #pragma unroll
            for (int dy = 0; dy < 3; ++dy)
                #pragma unroll
                for (int dx = 0; dx < 3; ++dx)
                    s = fmaf(w[dy * 3 + dx], r[dy][j + dx], s);
            o[j] = (_Float16)s;
            ssq = fmaf(s, s, ssq);
        }
        *(f16x8*)&g[u * 8] = o;
    }
    if (ch < 2 * C_) {
        #pragma unroll
        for (int m = 1; m < 64; m <<= 1) ssq += __shfl_xor(ssq, m);
        if ((t & 63) == 0) wsum[t >> 6] = ssq;
        __syncthreads();
        if (t == 0) {
            float tot = wsum[0] + wsum[1] + wsum[2] + wsum[3];
            float inv = 1.f / fmaxf(sqrtf(tot), 1e-12f);
            (ch < C_ ? nqinv : nkinv)[b * C_ + (ch % C_)] = inv;
        }
    }
}

// ---------------- MFMA scores: sp[ks][bh][48][48], ksplit=4, 4 waves/block ----------------
__global__ __launch_bounds__(256) void scores_mfma(
    const _Float16* __restrict__ buf, float* __restrict__ sp)
{
    const int bh = blockIdx.x;
    const int ks = blockIdx.y;
    const int b = bh >> 3, h = bh & 7;
    const _Float16* qbase = buf + ((size_t)b * C3_ + (size_t)h * D_) * HW_;
    const _Float16* kbase = qbase + (size_t)C_ * HW_;
    const int t = threadIdx.x, l = t & 63, w = t >> 6;
    const int frow = l & 15, kseg = (l >> 4) * 8;
    const int p0 = ks * 1024 + w * 256;

    f32x4 acc[3][3] = {};
    #pragma unroll 2
    for (int st = 0; st < 8; ++st) {
        const int p = p0 + st * 32 + kseg;
        f16x8 qf[3], kf[3];
        #pragma unroll
        for (int mi = 0; mi < 3; ++mi)
            qf[mi] = *(const f16x8*)&qbase[(size_t)(mi * 16 + frow) * HW_ + p];
        #pragma unroll
        for (int ni = 0; ni < 3; ++ni)
            kf[ni] = *(const f16x8*)&kbase[(size_t)(ni * 16 + frow) * HW_ + p];
        #pragma unroll
        for (int mi = 0; mi < 3; ++mi)
            #pragma unroll
            for (int ni = 0; ni < 3; ++ni)
                acc[mi][ni] = __builtin_amdgcn_mfma_f32_16x16x32_f16(
                    qf[mi], kf[ni], acc[mi][ni], 0, 0, 0);
    }
    __shared__ float red[4][D_ * D_];
    #pragma unroll
    for (int mi = 0; mi < 3; ++mi)
        #pragma unroll
        for (int ni = 0; ni < 3; ++ni)
            #pragma unroll
            for (int r = 0; r < 4; ++r)
                red[w][(mi * 16 + (l >> 4) * 4 + r) * D_ + ni * 16 + (l & 15)] =
                    acc[mi][ni][r];
    __syncthreads();
    float* out = sp + ((size_t)ks * 128 + bh) * (D_ * D_);
    const float* rf = &red[0][0];
    for (int i = t; i < D_ * D_; i += 256)
        out[i] = rf[i] + rf[2304 + i] + rf[4608 + i] + rf[6912 + i];
}

// ---------------- reduce partials, scale, softmax (4 rows / block) ----------------
__global__ __launch_bounds__(256) void softmax_k(
    const float* __restrict__ sp, const float* __restrict__ nqinv,
    const float* __restrict__ nkinv, const float* __restrict__ temp,
    float* __restrict__ attn)
{
    const int row = blockIdx.x * 4 + (threadIdx.x >> 6);
    const int bh = row / D_, d = row % D_;
    const int h = bh & 7;
    const int e = threadIdx.x & 63;
    float s = -INFINITY;
    if (e < D_) {
        float raw = 0.f;
        #pragma unroll
        for (int ks = 0; ks < 4; ++ks)
            raw += sp[((size_t)ks * 128 + bh) * (D_ * D_) + d * D_ + e];
        s = raw * nqinv[bh * D_ + d] * nkinv[bh * D_ + e] * temp[h];
    }
    float m = s;
    #pragma unroll
    for (int off = 1; off < 64; off <<= 1) m = fmaxf(m, __shfl_xor(m, off));
    float p = (e < D_) ? expf(s - m) : 0.f;
    float sum = p;
    #pragma unroll
    for (int off = 1; off < 64; off <<= 1) sum += __shfl_xor(sum, off);
    if (e < D_) attn[(size_t)bh * (D_ * D_) + d * D_ + e] = p / sum;
}

// ---------------- attn @ v -> fp16 transposed [pixel][384] into q-plane region ----------------
__global__ __launch_bounds__(256) void pv_kernel(
    _Float16* __restrict__ buf, const float* __restrict__ attn)
{
    const int b = blockIdx.z, h = blockIdx.y;
    const int p0 = blockIdx.x * 512 + threadIdx.x * 2;
    __shared__ float a4[48][48];
    const float* ab = attn + ((size_t)b * 8 + h) * (D_ * D_);
    for (int i = threadIdx.x; i < D_ * D_; i += 256) ((float*)a4)[i] = ab[i];
    __syncthreads();
    const _Float16* vbase = buf + ((size_t)b * C3_ + 2 * C_ + (size_t)h * D_) * HW_;
    float2 acc[48];
    #pragma unroll
    for (int d = 0; d < 48; ++d) { acc[d].x = 0.f; acc[d].y = 0.f; }
    #pragma unroll 1
    for (int e4 = 0; e4 < 12; ++e4) {
        float2 vv[4];
        #pragma unroll
        for (int j = 0; j < 4; ++j) {
            f16x2 h2 = *(const f16x2*)&vbase[(size_t)(e4 * 4 + j) * HW_ + p0];
            vv[j].x = (float)h2[0]; vv[j].y = (float)h2[1];
        }
        #pragma unroll
        for (int d = 0; d < 48; ++d) {
            float4 a = *(const float4*)&a4[d][e4 * 4];
            acc[d].x = fmaf(a.x, vv[0].x, fmaf(a.y, vv[1].x, fmaf(a.z, vv[2].x, fmaf(a.w, vv[3].x, acc[d].x))));
            acc[d].y = fmaf(a.x, vv[0].y, fmaf(a.y, vv[1].y, fmaf(a.z, vv[2].y, fmaf(a.w, vv[3].y, acc[d].y))));
        }
    }
    _Float16* xt2b = buf + (size_t)b * C3_ * HW_;   // q region, dead now
    #pragma unroll
    for (int px = 0; px < 2; ++px) {
        f16x8 tmp[6];
        #pragma unroll
        for (int d = 0; d < 48; ++d) tmp[d >> 3][d & 7] = (_Float16)(px ? acc[d].y : acc[d].x);
        f16x8* dst = (f16x8*)&xt2b[(size_t)(p0 + px) * C_ + h * D_];
        #pragma unroll
        for (int j = 0; j < 6; ++j) dst[j] = tmp[j];
    }
}

extern "C" void kernel_launch(void* const* d_in, const int* in_sizes, int n_in,
                              void* d_out, int out_size, void* d_ws, size_t ws_size,
                              hipStream_t stream)
{
    const float* x      = (const float*)d_in[0];
    const float* w_qkv  = (const float*)d_in[1];
    const float* w_dw   = (const float*)d_in[2];
    const float* w_proj = (const float*)d_in[3];
    const float* temp   = (const float*)d_in[4];
    float* out = (float*)d_out;

    _Float16* buf = (_Float16*)d_ws;                       // 16*1152*4096 halves
    float* nqinv = (float*)(buf + (size_t)B_ * C3_ * HW_);
    float* nkinv = nqinv + 6144;
    float* sp    = nkinv + 6144;                           // 4*128*2304 f
    float* attn  = sp + (size_t)4 * 128 * D_ * D_;         // 128*2304 f
    _Float16* wqkv_h  = (_Float16*)(attn + (size_t)128 * D_ * D_);
    _Float16* wproj_h = wqkv_h + (size_t)C3_ * C_;
    _Float16* xt1     = wproj_h + (size_t)C_ * C_;         // 16*4096*384 halves

    // 0) fused input transpose + weight conversion (one launch)
    prep_inputs<<<dim3(64, 6, 17), 256, 0, stream>>>(
        x, xt1, w_qkv, w_proj, wqkv_h, wproj_h);

    // 1) qkv = w_qkv @ x (GEMM, per-phase G-load interleave, fp16 out)
    mfma_gemm<C3_, false><<<dim3(9 * 16 * 16), 256, 0, stream>>>(
        wqkv_h, xt1, buf, (long long)HW_ * C_, (long long)C3_ * HW_);

    // 2) depthwise 3x3 SAME in place + fused q/k row norms
    dwconv_norm<<<B_ * C3_, 256, 0, stream>>>(buf, w_dw, nqinv, nkinv);

    // 3) raw score partials via MFMA (K split 4)
    scores_mfma<<<dim3(128, 4), 256, 0, stream>>>(buf, sp);

    // 4) reduce + scale + softmax
    softmax_k<<<1536, 256, 0, stream>>>(sp, nqinv, nkinv, temp, attn);

    // 5) attn @ v (VALU, validated) -> fp16 transposed into q region
    pv_kernel<<<dim3(8, 8, 16), 256, 0, stream>>>(buf, attn);

    // 6) out = w_proj @ attn_out (GEMM, per-phase G-load interleave, fp32 out)
    mfma_gemm<C_, true><<<dim3(3 * 16 * 16), 256, 0, stream>>>(
        wproj_h, buf, out, (long long)C3_ * HW_, (long long)C_ * HW_);
}